// Round 2
// baseline (259.335 us; speedup 1.0000x reference)
//
#include <hip/hip_runtime.h>

#define SEQ 1024
#define HID 2048
#define DIN 4096
#define NST 16
#define RNK 128
#define CHN 64
#define CLEN 16

typedef __attribute__((ext_vector_type(4))) float f32x4;
typedef __attribute__((ext_vector_type(4))) __bf16 bf16x4v;
typedef __attribute__((ext_vector_type(8))) __bf16 bf16x8v;
typedef __attribute__((ext_vector_type(8))) unsigned short u16x8;

#define GPTR(p) ((const __attribute__((address_space(1))) void*)(p))
#define LPTR(p) ((__attribute__((address_space(3))) void*)(p))

__device__ __forceinline__ unsigned short f2bf(float v) {
  unsigned u = __builtin_bit_cast(unsigned, v);
  u = (u + 0x7fffu + ((u >> 16) & 1u)) >> 16;
  return (unsigned short)u;
}
__device__ __forceinline__ float softplus_f(float x) {
  return (x > 20.f) ? x : log1pf(__expf(x));
}
__device__ __forceinline__ float silu_f(float x) {
  return x / (1.f + __expf(-x));
}

// ---------------- fp32 -> bf16 conversions, one launch, 8 elems/thread ----------------
#define CV_NX  (SEQ*HID)
#define CV_NW  (DIN*HID)
#define CV_NDT (RNK*DIN)
#define CV_NB  (NST*DIN)
#define CV_NPD (32*DIN)
#define CV_NWO (HID*DIN)
#define CV_TOT (CV_NX + 2*CV_NW + CV_NDT + 2*CV_NB + CV_NPD + CV_NDT + CV_NWO)

// All segment sizes are multiples of 512, so no wave straddles a segment
// boundary (64 lanes x 8 elems = 512). 32B load / 16B store per lane.
__global__ __launch_bounds__(256) void cvt_all(
    const float* __restrict__ x, const float* __restrict__ wis,
    const float* __restrict__ wig, const float* __restrict__ wdt,
    const float* __restrict__ wb, const float* __restrict__ wc,
    const float* __restrict__ wdtp, const float* __restrict__ wout,
    unsigned short* __restrict__ x_bf, unsigned short* __restrict__ wis_bf,
    unsigned short* __restrict__ wig_bf, unsigned short* __restrict__ wcat_bf,
    unsigned short* __restrict__ wdtp_bf, unsigned short* __restrict__ wout_bf)
{
  size_t j = ((size_t)blockIdx.x * 256 + threadIdx.x) * 8;
  const float* src = nullptr; unsigned short* dst;
  if (j < CV_NX) { src = x + j; dst = x_bf + j; }
  else if ((j -= CV_NX) < CV_NW) { src = wis + j; dst = wis_bf + j; }
  else if ((j -= CV_NW) < CV_NW) { src = wig + j; dst = wig_bf + j; }
  else if ((j -= CV_NW) < CV_NDT) { src = wdt + j; dst = wcat_bf + j; }
  else if ((j -= CV_NDT) < CV_NB) { src = wb + j; dst = wcat_bf + (size_t)128*DIN + j; }
  else if ((j -= CV_NB) < CV_NB) { src = wc + j; dst = wcat_bf + (size_t)144*DIN + j; }
  else if ((j -= CV_NB) < CV_NPD) { dst = wcat_bf + (size_t)160*DIN + j; }
  else if ((j -= CV_NPD) < CV_NDT) { src = wdtp + j; dst = wdtp_bf + j; }
  else { j -= CV_NDT; src = wout + j; dst = wout_bf + j; }
  u16x8 o = {};
  if (src) {
    f32x4 a = *(const f32x4*)src;
    f32x4 b = *(const f32x4*)(src + 4);
#pragma unroll
    for (int i = 0; i < 4; i++) { o[i] = f2bf(a[i]); o[4 + i] = f2bf(b[i]); }
  }
  *(u16x8*)dst = o;
}

// ---------------- m97-structure NT GEMM: 128x128 tile, BK=32, global_load_lds ----------------
// A: [M][Kstride] bf16, B: [N][Kstride] bf16, C: [M][N] fp32.
// grid.z>1 => split-K: slice z uses K-offset z*Kiter, writes C + z*M*N.
// XCD-aware swizzle over the (x,y) plane: requires gridDim.x*gridDim.y % 8 == 0
// (both call sites: 512 and 128). z-offset is a multiple of 8 blocks, so the
// round-robin XCD mapping is unchanged per-slice.
// EPI 0: plain. EPI 1: softplus(c + bias[col]).
template<int EPI>
__global__ __launch_bounds__(256) void gemm128(
    const unsigned short* __restrict__ Ag, const unsigned short* __restrict__ Bg,
    float* __restrict__ Cg, const float* __restrict__ bias,
    int Msz, int Nsz, int Kstride, int Kiter)
{
  __shared__ __align__(16) unsigned short As[128 * 32];
  __shared__ __align__(16) unsigned short Bs[128 * 32];
  const int kz = blockIdx.z;
  Ag += (size_t)kz * Kiter;
  Bg += (size_t)kz * Kiter;
  Cg += (size_t)kz * Msz * Nsz;
  const int nwg = gridDim.x * gridDim.y;
  const int orig = blockIdx.y * gridDim.x + blockIdx.x;
  const int swz = (orig & 7) * (nwg >> 3) + (orig >> 3);
  const int bx = swz % gridDim.x, by = swz / gridDim.x;
  const int tid = threadIdx.x;
  const int m0 = bx * 128, n0 = by * 128;
  const int lane = tid & 63, w = tid >> 6;
  const int wm = w >> 1, wn = w & 1;
  const int lg = lane >> 4, lr = lane & 15;
  const int srow = w * 32 + (lane >> 2);
  const int sch = (lane & 3) * 8;
  const unsigned short* Ag0 = Ag + (size_t)(m0 + srow) * Kstride + sch;
  const unsigned short* Bg0 = Bg + (size_t)(n0 + srow) * Kstride + sch;
  unsigned short* AsW = As + w * 1024;
  unsigned short* BsW = Bs + w * 1024;
  f32x4 acc[4][4] = {};
  for (int k0 = 0; k0 < Kiter; k0 += 32) {
    __builtin_amdgcn_global_load_lds(GPTR(Ag0 + k0), LPTR(AsW), 16, 0, 0);
    __builtin_amdgcn_global_load_lds(GPTR(Ag0 + 16 * Kstride + k0), LPTR(AsW + 512), 16, 0, 0);
    __builtin_amdgcn_global_load_lds(GPTR(Bg0 + k0), LPTR(BsW), 16, 0, 0);
    __builtin_amdgcn_global_load_lds(GPTR(Bg0 + 16 * Kstride + k0), LPTR(BsW + 512), 16, 0, 0);
    __syncthreads();
    bf16x8v af[4], bfv[4];
#pragma unroll
    for (int mi = 0; mi < 4; mi++)
      af[mi] = *(const bf16x8v*)&As[(wm * 64 + mi * 16 + lr) * 32 + lg * 8];
#pragma unroll
    for (int ni = 0; ni < 4; ni++)
      bfv[ni] = *(const bf16x8v*)&Bs[(wn * 64 + ni * 16 + lr) * 32 + lg * 8];
#pragma unroll
    for (int mi = 0; mi < 4; mi++)
#pragma unroll
      for (int ni = 0; ni < 4; ni++)
        acc[mi][ni] = __builtin_amdgcn_mfma_f32_16x16x32_bf16(af[mi], bfv[ni], acc[mi][ni], 0, 0, 0);
    __syncthreads();
  }
#pragma unroll
  for (int mi = 0; mi < 4; mi++) {
#pragma unroll
    for (int ni = 0; ni < 4; ni++) {
      const int col = n0 + wn * 64 + ni * 16 + lr;
#pragma unroll
      for (int r = 0; r < 4; r++) {
        const int row = m0 + wm * 64 + mi * 16 + lg * 4 + r;
        float v = acc[mi][ni][r];
        if (EPI == 1) v = softplus_f(v + bias[col]);
        Cg[(size_t)row * Nsz + col] = v;
      }
    }
  }
}

// ---------------- 128x64 NT GEMM, VGPR-staged (ts/B/C projection + dt-proj) ----------------
template<int EPI>
__global__ __launch_bounds__(256) void gemm_nt(
    const unsigned short* __restrict__ Ag, const unsigned short* __restrict__ Bg,
    float* __restrict__ Cg, const float* __restrict__ bias,
    int Msz, int Nsz, int Kstride, int Kiter)
{
  __shared__ __align__(16) unsigned short As[128][40];
  __shared__ __align__(16) unsigned short Bs[64][40];
  const int kz = blockIdx.z;
  Ag += (size_t)kz * Kiter;
  Bg += (size_t)kz * Kiter;
  Cg += (size_t)kz * Msz * Nsz;
  const int tid = threadIdx.x;
  const int m0 = blockIdx.x * 128, n0 = blockIdx.y * 64;
  const int lane = tid & 63, w = tid >> 6;
  const int wm = w >> 1, wn = w & 1;
  const int lg = lane >> 4, lr = lane & 15;
  const int r4 = tid >> 2, c8 = (tid & 3) * 8;
  f32x4 acc[4][2] = {};
  for (int k0 = 0; k0 < Kiter; k0 += 32) {
    uint4 a0 = *(const uint4*)(Ag + (size_t)(m0 + r4) * Kstride + k0 + c8);
    uint4 a1 = *(const uint4*)(Ag + (size_t)(m0 + 64 + r4) * Kstride + k0 + c8);
    uint4 b0 = *(const uint4*)(Bg + (size_t)(n0 + r4) * Kstride + k0 + c8);
    *(uint4*)&As[r4][c8] = a0;
    *(uint4*)&As[64 + r4][c8] = a1;
    *(uint4*)&Bs[r4][c8] = b0;
    __syncthreads();
    bf16x8v af[4], bfr[2];
#pragma unroll
    for (int mi = 0; mi < 4; mi++) {
      const int row = wm * 64 + mi * 16 + lr;
      bf16x4v lo = *(const bf16x4v*)&As[row][4 * lg];
      bf16x4v hi = *(const bf16x4v*)&As[row][16 + 4 * lg];
      af[mi] = __builtin_shufflevector(lo, hi, 0, 1, 2, 3, 4, 5, 6, 7);
    }
#pragma unroll
    for (int ni = 0; ni < 2; ni++) {
      const int row = wn * 32 + ni * 16 + lr;
      bf16x4v lo = *(const bf16x4v*)&Bs[row][4 * lg];
      bf16x4v hi = *(const bf16x4v*)&Bs[row][16 + 4 * lg];
      bfr[ni] = __builtin_shufflevector(lo, hi, 0, 1, 2, 3, 4, 5, 6, 7);
    }
#pragma unroll
    for (int mi = 0; mi < 4; mi++)
#pragma unroll
      for (int ni = 0; ni < 2; ni++)
        acc[mi][ni] = __builtin_amdgcn_mfma_f32_16x16x32_bf16(af[mi], bfr[ni], acc[mi][ni], 0, 0, 0);
    __syncthreads();
  }
#pragma unroll
  for (int mi = 0; mi < 4; mi++) {
#pragma unroll
    for (int ni = 0; ni < 2; ni++) {
      const int col = n0 + wn * 32 + ni * 16 + lr;
#pragma unroll
      for (int r = 0; r < 4; r++) {
        const int row = m0 + wm * 64 + mi * 16 + lg * 4 + r;
        float v = acc[mi][ni][r];
        if (EPI == 1) v = softplus_f(v + bias[col]);
        Cg[(size_t)row * Nsz + col] = v;
      }
    }
  }
}

// ---------------- causal depthwise conv(K=4) + bias + silu ----------------
// pg now holds TWO split-K partials of the in-proj: pg[z][SEQ][8192], z=0,1.
// The partial-sum reduce is fused here (state half) and in scan_phase3 (gate half).
__global__ __launch_bounds__(256) void conv_silu(
    const float* __restrict__ pg, const float* __restrict__ cw,
    const float* __restrict__ cb, float* __restrict__ hs,
    unsigned short* __restrict__ hs_bf)
{
  const size_t ZOFF = (size_t)SEQ * 8192;
  int idx = blockIdx.x * 256 + threadIdx.x;  // l*DIN + d
  int l = idx >> 12, d = idx & (DIN - 1);
  float acc = cb[d];
#pragma unroll
  for (int j = 0; j < 4; j++) {
    int ll = l + j - 3;
    float v = (ll >= 0) ? pg[(size_t)ll * 8192 + d] + pg[ZOFF + (size_t)ll * 8192 + d] : 0.f;
    acc = fmaf(cw[d * 4 + j], v, acc);
  }
  float r = silu_f(acc);
  hs[idx] = r;
  hs_bf[idx] = f2bf(r);
}

// ---------------- split-K reduce for ts/B/C + ts->bf16 ----------------
__global__ __launch_bounds__(256) void reduce_ts(
    const float* __restrict__ c2p, float* __restrict__ c2,
    unsigned short* __restrict__ ts_bf)
{
  int i = blockIdx.x * 256 + threadIdx.x;  // < SEQ*192
  float s = 0.f;
#pragma unroll
  for (int z = 0; z < 8; z++) s += c2p[(size_t)z * SEQ * 192 + i];
  c2[i] = s;
  int l = i / 192, col = i - l * 192;
  if (col < 128) ts_bf[l * 128 + col] = f2bf(s);
}

// ---------------- split-K reduce for out-proj (x2, float4) ----------------
__global__ __launch_bounds__(256) void reduce_out(
    const float* __restrict__ p, float* __restrict__ out)
{
  int i = (blockIdx.x * 256 + threadIdx.x) * 4;
  float4 a = *(const float4*)&p[i];
  float4 b = *(const float4*)&p[(size_t)SEQ * HID + i];
  a.x += b.x; a.y += b.y; a.z += b.z; a.w += b.w;
  *(float4*)&out[i] = a;
}

// ---------------- chunked selective scan ----------------
__global__ __launch_bounds__(256) void scan_phase1(
    const float* __restrict__ dt, const float* __restrict__ hs,
    const float* __restrict__ c2, const float* __restrict__ alog,
    float* __restrict__ Pbuf, float* __restrict__ Sbuf)
{
  __shared__ float B_ch[CLEN][16];
  const int tid = threadIdx.x;
  const int d = blockIdx.x * 256 + tid;
  const int c = blockIdx.y;
  const int l0 = c * CLEN;
  B_ch[tid >> 4][tid & 15] = c2[(size_t)(l0 + (tid >> 4)) * 192 + 128 + (tid & 15)];
  float a[16];
#pragma unroll
  for (int i = 0; i < 16; i++) a[i] = -__expf(alog[(size_t)d * 16 + i]);
  __syncthreads();
  float s[16] = {};
  float P[16];
#pragma unroll
  for (int i = 0; i < 16; i++) P[i] = 1.f;
  for (int t = 0; t < CLEN; t++) {
    float dtv = dt[(size_t)(l0 + t) * DIN + d];
    float u = hs[(size_t)(l0 + t) * DIN + d];
    float w = dtv * u;
#pragma unroll
    for (int n = 0; n < 16; n++) {
      float dA = __expf(a[n] * dtv);
      s[n] = fmaf(dA, s[n], w * B_ch[t][n]);
      P[n] *= dA;
    }
  }
  size_t base = ((size_t)c * DIN + d) * 16;
#pragma unroll
  for (int i = 0; i < 4; i++) {
    *(float4*)&Sbuf[base + 4 * i] = *(float4*)&s[4 * i];
    *(float4*)&Pbuf[base + 4 * i] = *(float4*)&P[4 * i];
  }
}

// phase 2: serial combine; sig written IN-PLACE into Sbuf
__global__ __launch_bounds__(256) void scan_phase2(
    const float* __restrict__ Pbuf, float* __restrict__ Sbuf)
{
  size_t idx = (size_t)blockIdx.x * 256 + threadIdx.x;  // d*16+n
  const size_t stride = (size_t)DIN * 16;
  float s = 0.f;
#pragma unroll 4
  for (int c = 0; c < CHN; c++) {
    float Pv = Pbuf[c * stride + idx];
    float Sv = Sbuf[c * stride + idx];
    Sbuf[c * stride + idx] = s;
    s = fmaf(Pv, s, Sv);
  }
}

// phase 3: re-scan chunk from sig (=Sbuf), y = s.C, fused D + gate (two partials), write ygT bf16
__global__ __launch_bounds__(256) void scan_phase3(
    const float* __restrict__ dt, const float* __restrict__ hs,
    const float* __restrict__ pg, const float* __restrict__ c2,
    const float* __restrict__ alog, const float* __restrict__ Dv,
    const float* __restrict__ sig, unsigned short* __restrict__ ygT)
{
  __shared__ float B_ch[CLEN][16], C_ch[CLEN][16];
  const size_t ZOFF = (size_t)SEQ * 8192;
  const int tid = threadIdx.x;
  const int d = blockIdx.x * 256 + tid;
  const int c = blockIdx.y;
  const int l0 = c * CLEN;
  {
    int t = tid >> 4, n = tid & 15;
    B_ch[t][n] = c2[(size_t)(l0 + t) * 192 + 128 + n];
    C_ch[t][n] = c2[(size_t)(l0 + t) * 192 + 144 + n];
  }
  float a[16];
#pragma unroll
  for (int i = 0; i < 16; i++) a[i] = -__expf(alog[(size_t)d * 16 + i]);
  const float Dd = Dv[d];
  float s[16];
  size_t base = ((size_t)c * DIN + d) * 16;
#pragma unroll
  for (int i = 0; i < 4; i++) *(float4*)&s[4 * i] = *(const float4*)&sig[base + 4 * i];
  __syncthreads();
  for (int t = 0; t < CLEN; t++) {
    float dtv = dt[(size_t)(l0 + t) * DIN + d];
    float u = hs[(size_t)(l0 + t) * DIN + d];
    size_t goff = (size_t)(l0 + t) * 8192 + 4096 + d;
    float g = pg[goff] + pg[ZOFF + goff];
    float w = dtv * u;
    float y = 0.f;
#pragma unroll
    for (int n = 0; n < 16; n++) {
      float dA = __expf(a[n] * dtv);
      s[n] = fmaf(dA, s[n], w * B_ch[t][n]);
      y = fmaf(s[n], C_ch[t][n], y);
    }
    float o = (y + u * Dd) * silu_f(g);
    ygT[(size_t)(l0 + t) * DIN + d] = f2bf(o);
  }
}

extern "C" void kernel_launch(void* const* d_in, const int* in_sizes, int n_in,
                              void* d_out, int out_size, void* d_ws, size_t ws_size,
                              hipStream_t stream) {
  const float* x     = (const float*)d_in[0];
  const float* wis   = (const float*)d_in[1];
  const float* wig   = (const float*)d_in[2];
  const float* convw = (const float*)d_in[3];
  const float* convb = (const float*)d_in[4];
  const float* wdt   = (const float*)d_in[5];
  const float* wb    = (const float*)d_in[6];
  const float* wc    = (const float*)d_in[7];
  const float* wdtp  = (const float*)d_in[8];
  const float* bdtp  = (const float*)d_in[9];
  const float* alog  = (const float*)d_in[10];
  const float* Dv    = (const float*)d_in[11];
  const float* wout  = (const float*)d_in[12];

  char* ws = (char*)d_ws;
  size_t off = 0;
  auto alloc = [&](size_t bytes) { void* p = ws + off; off += (bytes + 255) & ~(size_t)255; return p; };
  unsigned short* x_bf    = (unsigned short*)alloc((size_t)SEQ * HID * 2);
  unsigned short* wis_bf  = (unsigned short*)alloc((size_t)DIN * HID * 2);  // adjacent to wig_bf: one [8192][2048] B matrix
  unsigned short* wig_bf  = (unsigned short*)alloc((size_t)DIN * HID * 2);
  unsigned short* wcat_bf = (unsigned short*)alloc((size_t)192 * DIN * 2);
  unsigned short* wdtp_bf = (unsigned short*)alloc((size_t)DIN * RNK * 2);
  unsigned short* wout_bf = (unsigned short*)alloc((size_t)HID * DIN * 2);
  float* pg    = (float*)alloc((size_t)2 * SEQ * 8192 * 4);  // [2][SEQ][8192] split-K partials: cols 0..4095 states, 4096..8191 gate
  float* hs2   = (float*)alloc((size_t)SEQ * DIN * 4);   // hs post conv+silu [SEQ][DIN]
  unsigned short* hs_bf = (unsigned short*)alloc((size_t)SEQ * DIN * 2);
  float* c2    = (float*)alloc((size_t)SEQ * 192 * 4);
  float* c2p   = (float*)alloc((size_t)8 * SEQ * 192 * 4);
  unsigned short* ts_bf = (unsigned short*)alloc((size_t)SEQ * RNK * 2);
  float* dtbuf = (float*)alloc((size_t)SEQ * DIN * 4);
  unsigned short* ygT_bf = (unsigned short*)alloc((size_t)SEQ * DIN * 2);
  if (off > ws_size) return;  // workspace too small: fail loudly via validation
  // dead-buffer reuse (16 MB each): wis_bf/wig_bf dead after in-proj; dtbuf dead after scan
  float* Pbuf = (float*)wis_bf;
  float* Sbuf = (float*)wig_bf;   // phase2 overwrites with sig in-place
  float* op_part = dtbuf;         // [2][SEQ][HID] out-proj partials

  // 1) all bf16 conversions (8 elems/thread: 2x float4 load, ushort8 store)
  cvt_all<<<CV_TOT / 2048, 256, 0, stream>>>(x, wis, wig, wdt, wb, wc, wdtp, wout,
                                             x_bf, wis_bf, wig_bf, wcat_bf, wdtp_bf, wout_bf);
  // 2) merged input projection, split-K x2 (1024 blocks -> 4 blk/CU), XCD swizzle:
  //    pg[z][SEQ][8192] = x[SEQ][1024-slice] x [wis;wig][8192][1024-slice]
  gemm128<0><<<dim3(SEQ / 128, 8192 / 128, 2), 256, 0, stream>>>(x_bf, wis_bf, pg, nullptr, SEQ, 8192, HID, HID / 2);
  // 3) causal conv + silu + bf16 cast (fused in-proj partial reduce, state half)
  conv_silu<<<(SEQ * DIN) / 256, 256, 0, stream>>>(pg, convw, convb, hs2, hs_bf);
  // 4) ts/B/C projections, split-K x8
  gemm_nt<0><<<dim3(SEQ / 128, 192 / 64, 8), 256, 0, stream>>>(hs_bf, wcat_bf, c2p, nullptr, SEQ, 192, DIN, DIN / 8);
  reduce_ts<<<(SEQ * 192) / 256, 256, 0, stream>>>(c2p, c2, ts_bf);
  // 5) dt[SEQ][DIN] = softplus(ts[SEQ][RNK] x Wdtproj[DIN][RNK] + b)
  gemm_nt<1><<<dim3(SEQ / 128, DIN / 64), 256, 0, stream>>>(ts_bf, wdtp_bf, dtbuf, bdtp, SEQ, DIN, RNK, RNK);
  // 6) chunked selective scan (64 chunks of 16)
  scan_phase1<<<dim3(DIN / 256, CHN), 256, 0, stream>>>(dtbuf, hs2, c2, alog, Pbuf, Sbuf);
  scan_phase2<<<(DIN * NST) / 256, 256, 0, stream>>>(Pbuf, Sbuf);
  scan_phase3<<<dim3(DIN / 256, CHN), 256, 0, stream>>>(dtbuf, hs2, pg, c2, alog, Dv, Sbuf, ygT_bf);
  // 7) out-proj split-K x2: op_part[z][SEQ][HID] = ygT[SEQ][2048-slice] x Wout[HID][2048-slice]
  gemm128<0><<<dim3(SEQ / 128, HID / 128, 2), 256, 0, stream>>>(ygT_bf, wout_bf, op_part, nullptr, SEQ, HID, DIN, DIN / 2);
  reduce_out<<<(SEQ * HID) / 1024, 256, 0, stream>>>(op_part, (float*)d_out);
}

// Round 3
// 238.830 us; speedup vs baseline: 1.0859x; 1.0859x over previous
//
#include <hip/hip_runtime.h>

#define SEQ 1024
#define HID 2048
#define DIN 4096
#define NST 16
#define RNK 128
#define CHN 64
#define CLEN 16

typedef __attribute__((ext_vector_type(4))) float f32x4;
typedef __attribute__((ext_vector_type(4))) __bf16 bf16x4v;
typedef __attribute__((ext_vector_type(8))) __bf16 bf16x8v;
typedef __attribute__((ext_vector_type(8))) unsigned short u16x8;

#define GPTR(p) ((const __attribute__((address_space(1))) void*)(p))
#define LPTR(p) ((__attribute__((address_space(3))) void*)(p))

__device__ __forceinline__ unsigned short f2bf(float v) {
  unsigned u = __builtin_bit_cast(unsigned, v);
  u = (u + 0x7fffu + ((u >> 16) & 1u)) >> 16;
  return (unsigned short)u;
}
__device__ __forceinline__ float softplus_f(float x) {
  return (x > 20.f) ? x : log1pf(__expf(x));
}
__device__ __forceinline__ float silu_f(float x) {
  return x / (1.f + __expf(-x));
}

// ---------------- fp32 -> bf16 conversions, one launch, 8 elems/thread ----------------
#define CV_NX  (SEQ*HID)
#define CV_NW  (DIN*HID)
#define CV_NDT (RNK*DIN)
#define CV_NB  (NST*DIN)
#define CV_NPD (32*DIN)
#define CV_NWO (HID*DIN)
#define CV_TOT (CV_NX + 2*CV_NW + CV_NDT + 2*CV_NB + CV_NPD + CV_NDT + CV_NWO)

// All segment sizes are multiples of 512, so no wave straddles a segment
// boundary (64 lanes x 8 elems = 512). 32B load / 16B store per lane.
__global__ __launch_bounds__(256) void cvt_all(
    const float* __restrict__ x, const float* __restrict__ wis,
    const float* __restrict__ wig, const float* __restrict__ wdt,
    const float* __restrict__ wb, const float* __restrict__ wc,
    const float* __restrict__ wdtp, const float* __restrict__ wout,
    unsigned short* __restrict__ x_bf, unsigned short* __restrict__ wis_bf,
    unsigned short* __restrict__ wig_bf, unsigned short* __restrict__ wcat_bf,
    unsigned short* __restrict__ wdtp_bf, unsigned short* __restrict__ wout_bf)
{
  size_t j = ((size_t)blockIdx.x * 256 + threadIdx.x) * 8;
  const float* src = nullptr; unsigned short* dst;
  if (j < CV_NX) { src = x + j; dst = x_bf + j; }
  else if ((j -= CV_NX) < CV_NW) { src = wis + j; dst = wis_bf + j; }
  else if ((j -= CV_NW) < CV_NW) { src = wig + j; dst = wig_bf + j; }
  else if ((j -= CV_NW) < CV_NDT) { src = wdt + j; dst = wcat_bf + j; }
  else if ((j -= CV_NDT) < CV_NB) { src = wb + j; dst = wcat_bf + (size_t)128*DIN + j; }
  else if ((j -= CV_NB) < CV_NB) { src = wc + j; dst = wcat_bf + (size_t)144*DIN + j; }
  else if ((j -= CV_NB) < CV_NPD) { dst = wcat_bf + (size_t)160*DIN + j; }
  else if ((j -= CV_NPD) < CV_NDT) { src = wdtp + j; dst = wdtp_bf + j; }
  else { j -= CV_NDT; src = wout + j; dst = wout_bf + j; }
  u16x8 o = {};
  if (src) {
    f32x4 a = *(const f32x4*)src;
    f32x4 b = *(const f32x4*)(src + 4);
#pragma unroll
    for (int i = 0; i < 4; i++) { o[i] = f2bf(a[i]); o[4 + i] = f2bf(b[i]); }
  }
  *(u16x8*)dst = o;
}

// ---------------- pipelined NT GEMM: 128x128 tile, BK=32, 2-deep prefetch ----------------
// A: [M][Kstride] bf16, B: [N][Kstride] bf16, C: [M][N] fp32.
// 3 LDS buffers; counted s_waitcnt vmcnt(4) keeps the next tile's loads in
// flight across the (raw) barrier -- one barrier per K-step, load latency
// hidden under two K-steps of compute (T3/T4 minimum recipe).
// grid.z>1 => split-K. XCD swizzle needs gridDim.x*gridDim.y % 8 == 0.
// Requires Kiter >= 64 (nt >= 2).
template<int EPI>
__global__ __launch_bounds__(256) void gemm128(
    const unsigned short* __restrict__ Ag, const unsigned short* __restrict__ Bg,
    float* __restrict__ Cg, const float* __restrict__ bias,
    int Msz, int Nsz, int Kstride, int Kiter)
{
  __shared__ __align__(16) unsigned short As[3][128 * 32];
  __shared__ __align__(16) unsigned short Bs[3][128 * 32];
  const int kz = blockIdx.z;
  Ag += (size_t)kz * Kiter;
  Bg += (size_t)kz * Kiter;
  Cg += (size_t)kz * Msz * Nsz;
  const int nwg = gridDim.x * gridDim.y;
  const int orig = blockIdx.y * gridDim.x + blockIdx.x;
  const int swz = (orig & 7) * (nwg >> 3) + (orig >> 3);
  const int bx = swz % gridDim.x, by = swz / gridDim.x;
  const int tid = threadIdx.x;
  const int m0 = bx * 128, n0 = by * 128;
  const int lane = tid & 63, w = tid >> 6;
  const int wm = w >> 1, wn = w & 1;
  const int lg = lane >> 4, lr = lane & 15;
  const int srow = w * 32 + (lane >> 2);
  const int sch = (lane & 3) * 8;
  const unsigned short* Ag0 = Ag + (size_t)(m0 + srow) * Kstride + sch;
  const unsigned short* Bg0 = Bg + (size_t)(n0 + srow) * Kstride + sch;
  const int wo = w * 1024;

  auto stage = [&](int b, int k0) {
    __builtin_amdgcn_global_load_lds(GPTR(Ag0 + k0), LPTR(&As[b][wo]), 16, 0, 0);
    __builtin_amdgcn_global_load_lds(GPTR(Ag0 + 16 * Kstride + k0), LPTR(&As[b][wo + 512]), 16, 0, 0);
    __builtin_amdgcn_global_load_lds(GPTR(Bg0 + k0), LPTR(&Bs[b][wo]), 16, 0, 0);
    __builtin_amdgcn_global_load_lds(GPTR(Bg0 + 16 * Kstride + k0), LPTR(&Bs[b][wo + 512]), 16, 0, 0);
  };

  const int nt = Kiter >> 5;
  stage(0, 0);
  stage(1, 32);
  f32x4 acc[4][4] = {};
  int cur = 0, pf = 2;
  for (int t = 0; t < nt; ++t) {
    if (t < nt - 1) {
      asm volatile("s_waitcnt vmcnt(4)" ::: "memory");
    } else {
      asm volatile("s_waitcnt vmcnt(0)" ::: "memory");
    }
    __builtin_amdgcn_s_barrier();
    asm volatile("" ::: "memory");
    if (t + 2 < nt) stage(pf, (t + 2) * 32);
    bf16x8v af[4], bfv[4];
#pragma unroll
    for (int mi = 0; mi < 4; mi++)
      af[mi] = *(const bf16x8v*)&As[cur][(wm * 64 + mi * 16 + lr) * 32 + lg * 8];
#pragma unroll
    for (int ni = 0; ni < 4; ni++)
      bfv[ni] = *(const bf16x8v*)&Bs[cur][(wn * 64 + ni * 16 + lr) * 32 + lg * 8];
#pragma unroll
    for (int mi = 0; mi < 4; mi++)
#pragma unroll
      for (int ni = 0; ni < 4; ni++)
        acc[mi][ni] = __builtin_amdgcn_mfma_f32_16x16x32_bf16(af[mi], bfv[ni], acc[mi][ni], 0, 0, 0);
    cur = (cur == 2) ? 0 : cur + 1;
    pf = (pf == 2) ? 0 : pf + 1;
  }
#pragma unroll
  for (int mi = 0; mi < 4; mi++) {
#pragma unroll
    for (int ni = 0; ni < 4; ni++) {
      const int col = n0 + wn * 64 + ni * 16 + lr;
#pragma unroll
      for (int r = 0; r < 4; r++) {
        const int row = m0 + wm * 64 + mi * 16 + lg * 4 + r;
        float v = acc[mi][ni][r];
        if (EPI == 1) v = softplus_f(v + bias[col]);
        Cg[(size_t)row * Nsz + col] = v;
      }
    }
  }
}

// ---------------- 128x64 NT GEMM, VGPR-staged (ts/B/C projection + dt-proj) ----------------
template<int EPI>
__global__ __launch_bounds__(256) void gemm_nt(
    const unsigned short* __restrict__ Ag, const unsigned short* __restrict__ Bg,
    float* __restrict__ Cg, const float* __restrict__ bias,
    int Msz, int Nsz, int Kstride, int Kiter)
{
  __shared__ __align__(16) unsigned short As[128][40];
  __shared__ __align__(16) unsigned short Bs[64][40];
  const int kz = blockIdx.z;
  Ag += (size_t)kz * Kiter;
  Bg += (size_t)kz * Kiter;
  Cg += (size_t)kz * Msz * Nsz;
  const int tid = threadIdx.x;
  const int m0 = blockIdx.x * 128, n0 = blockIdx.y * 64;
  const int lane = tid & 63, w = tid >> 6;
  const int wm = w >> 1, wn = w & 1;
  const int lg = lane >> 4, lr = lane & 15;
  const int r4 = tid >> 2, c8 = (tid & 3) * 8;
  f32x4 acc[4][2] = {};
  for (int k0 = 0; k0 < Kiter; k0 += 32) {
    uint4 a0 = *(const uint4*)(Ag + (size_t)(m0 + r4) * Kstride + k0 + c8);
    uint4 a1 = *(const uint4*)(Ag + (size_t)(m0 + 64 + r4) * Kstride + k0 + c8);
    uint4 b0 = *(const uint4*)(Bg + (size_t)(n0 + r4) * Kstride + k0 + c8);
    *(uint4*)&As[r4][c8] = a0;
    *(uint4*)&As[64 + r4][c8] = a1;
    *(uint4*)&Bs[r4][c8] = b0;
    __syncthreads();
    bf16x8v af[4], bfr[2];
#pragma unroll
    for (int mi = 0; mi < 4; mi++) {
      const int row = wm * 64 + mi * 16 + lr;
      bf16x4v lo = *(const bf16x4v*)&As[row][4 * lg];
      bf16x4v hi = *(const bf16x4v*)&As[row][16 + 4 * lg];
      af[mi] = __builtin_shufflevector(lo, hi, 0, 1, 2, 3, 4, 5, 6, 7);
    }
#pragma unroll
    for (int ni = 0; ni < 2; ni++) {
      const int row = wn * 32 + ni * 16 + lr;
      bf16x4v lo = *(const bf16x4v*)&Bs[row][4 * lg];
      bf16x4v hi = *(const bf16x4v*)&Bs[row][16 + 4 * lg];
      bfr[ni] = __builtin_shufflevector(lo, hi, 0, 1, 2, 3, 4, 5, 6, 7);
    }
#pragma unroll
    for (int mi = 0; mi < 4; mi++)
#pragma unroll
      for (int ni = 0; ni < 2; ni++)
        acc[mi][ni] = __builtin_amdgcn_mfma_f32_16x16x32_bf16(af[mi], bfr[ni], acc[mi][ni], 0, 0, 0);
    __syncthreads();
  }
#pragma unroll
  for (int mi = 0; mi < 4; mi++) {
#pragma unroll
    for (int ni = 0; ni < 2; ni++) {
      const int col = n0 + wn * 32 + ni * 16 + lr;
#pragma unroll
      for (int r = 0; r < 4; r++) {
        const int row = m0 + wm * 64 + mi * 16 + lg * 4 + r;
        float v = acc[mi][ni][r];
        if (EPI == 1) v = softplus_f(v + bias[col]);
        Cg[(size_t)row * Nsz + col] = v;
      }
    }
  }
}

// ---------------- causal depthwise conv(K=4) + bias + silu; pg stride 8192 ----------------
__global__ __launch_bounds__(256) void conv_silu(
    const float* __restrict__ pg, const float* __restrict__ cw,
    const float* __restrict__ cb, float* __restrict__ hs,
    unsigned short* __restrict__ hs_bf)
{
  int idx = blockIdx.x * 256 + threadIdx.x;  // l*DIN + d
  int l = idx >> 12, d = idx & (DIN - 1);
  float acc = cb[d];
#pragma unroll
  for (int j = 0; j < 4; j++) {
    int ll = l + j - 3;
    float v = (ll >= 0) ? pg[(size_t)ll * 8192 + d] : 0.f;
    acc = fmaf(cw[d * 4 + j], v, acc);
  }
  float r = silu_f(acc);
  hs[idx] = r;
  hs_bf[idx] = f2bf(r);
}

// ---------------- split-K reduce for ts/B/C + ts->bf16 ----------------
__global__ __launch_bounds__(256) void reduce_ts(
    const float* __restrict__ c2p, float* __restrict__ c2,
    unsigned short* __restrict__ ts_bf)
{
  int i = blockIdx.x * 256 + threadIdx.x;  // < SEQ*192
  float s = 0.f;
#pragma unroll
  for (int z = 0; z < 8; z++) s += c2p[(size_t)z * SEQ * 192 + i];
  c2[i] = s;
  int l = i / 192, col = i - l * 192;
  if (col < 128) ts_bf[l * 128 + col] = f2bf(s);
}

// ---------------- split-K reduce for out-proj (x2, float4) ----------------
__global__ __launch_bounds__(256) void reduce_out(
    const float* __restrict__ p, float* __restrict__ out)
{
  int i = (blockIdx.x * 256 + threadIdx.x) * 4;
  float4 a = *(const float4*)&p[i];
  float4 b = *(const float4*)&p[(size_t)SEQ * HID + i];
  a.x += b.x; a.y += b.y; a.z += b.z; a.w += b.w;
  *(float4*)&out[i] = a;
}

// ---------------- chunked selective scan ----------------
__global__ __launch_bounds__(256) void scan_phase1(
    const float* __restrict__ dt, const float* __restrict__ hs,
    const float* __restrict__ c2, const float* __restrict__ alog,
    float* __restrict__ Pbuf, float* __restrict__ Sbuf)
{
  __shared__ float B_ch[CLEN][16];
  const int tid = threadIdx.x;
  const int d = blockIdx.x * 256 + tid;
  const int c = blockIdx.y;
  const int l0 = c * CLEN;
  B_ch[tid >> 4][tid & 15] = c2[(size_t)(l0 + (tid >> 4)) * 192 + 128 + (tid & 15)];
  float a[16];
#pragma unroll
  for (int i = 0; i < 16; i++) a[i] = -__expf(alog[(size_t)d * 16 + i]);
  __syncthreads();
  float s[16] = {};
  float P[16];
#pragma unroll
  for (int i = 0; i < 16; i++) P[i] = 1.f;
  for (int t = 0; t < CLEN; t++) {
    float dtv = dt[(size_t)(l0 + t) * DIN + d];
    float u = hs[(size_t)(l0 + t) * DIN + d];
    float w = dtv * u;
#pragma unroll
    for (int n = 0; n < 16; n++) {
      float dA = __expf(a[n] * dtv);
      s[n] = fmaf(dA, s[n], w * B_ch[t][n]);
      P[n] *= dA;
    }
  }
  size_t base = ((size_t)c * DIN + d) * 16;
#pragma unroll
  for (int i = 0; i < 4; i++) {
    *(float4*)&Sbuf[base + 4 * i] = *(float4*)&s[4 * i];
    *(float4*)&Pbuf[base + 4 * i] = *(float4*)&P[4 * i];
  }
}

// phase 2: serial combine; sig written IN-PLACE into Sbuf
__global__ __launch_bounds__(256) void scan_phase2(
    const float* __restrict__ Pbuf, float* __restrict__ Sbuf)
{
  size_t idx = (size_t)blockIdx.x * 256 + threadIdx.x;  // d*16+n
  const size_t stride = (size_t)DIN * 16;
  float s = 0.f;
#pragma unroll 4
  for (int c = 0; c < CHN; c++) {
    float Pv = Pbuf[c * stride + idx];
    float Sv = Sbuf[c * stride + idx];
    Sbuf[c * stride + idx] = s;
    s = fmaf(Pv, s, Sv);
  }
}

// phase 3: re-scan chunk from sig (=Sbuf), y = s.C, fused D + gate, write ygT bf16
__global__ __launch_bounds__(256) void scan_phase3(
    const float* __restrict__ dt, const float* __restrict__ hs,
    const float* __restrict__ pg, const float* __restrict__ c2,
    const float* __restrict__ alog, const float* __restrict__ Dv,
    const float* __restrict__ sig, unsigned short* __restrict__ ygT)
{
  __shared__ float B_ch[CLEN][16], C_ch[CLEN][16];
  const int tid = threadIdx.x;
  const int d = blockIdx.x * 256 + tid;
  const int c = blockIdx.y;
  const int l0 = c * CLEN;
  {
    int t = tid >> 4, n = tid & 15;
    B_ch[t][n] = c2[(size_t)(l0 + t) * 192 + 128 + n];
    C_ch[t][n] = c2[(size_t)(l0 + t) * 192 + 144 + n];
  }
  float a[16];
#pragma unroll
  for (int i = 0; i < 16; i++) a[i] = -__expf(alog[(size_t)d * 16 + i]);
  const float Dd = Dv[d];
  float s[16];
  size_t base = ((size_t)c * DIN + d) * 16;
#pragma unroll
  for (int i = 0; i < 4; i++) *(float4*)&s[4 * i] = *(const float4*)&sig[base + 4 * i];
  __syncthreads();
  for (int t = 0; t < CLEN; t++) {
    float dtv = dt[(size_t)(l0 + t) * DIN + d];
    float u = hs[(size_t)(l0 + t) * DIN + d];
    float g = pg[(size_t)(l0 + t) * 8192 + 4096 + d];
    float w = dtv * u;
    float y = 0.f;
#pragma unroll
    for (int n = 0; n < 16; n++) {
      float dA = __expf(a[n] * dtv);
      s[n] = fmaf(dA, s[n], w * B_ch[t][n]);
      y = fmaf(s[n], C_ch[t][n], y);
    }
    float o = (y + u * Dd) * silu_f(g);
    ygT[(size_t)(l0 + t) * DIN + d] = f2bf(o);
  }
}

extern "C" void kernel_launch(void* const* d_in, const int* in_sizes, int n_in,
                              void* d_out, int out_size, void* d_ws, size_t ws_size,
                              hipStream_t stream) {
  const float* x     = (const float*)d_in[0];
  const float* wis   = (const float*)d_in[1];
  const float* wig   = (const float*)d_in[2];
  const float* convw = (const float*)d_in[3];
  const float* convb = (const float*)d_in[4];
  const float* wdt   = (const float*)d_in[5];
  const float* wb    = (const float*)d_in[6];
  const float* wc    = (const float*)d_in[7];
  const float* wdtp  = (const float*)d_in[8];
  const float* bdtp  = (const float*)d_in[9];
  const float* alog  = (const float*)d_in[10];
  const float* Dv    = (const float*)d_in[11];
  const float* wout  = (const float*)d_in[12];

  char* ws = (char*)d_ws;
  size_t off = 0;
  auto alloc = [&](size_t bytes) { void* p = ws + off; off += (bytes + 255) & ~(size_t)255; return p; };
  unsigned short* x_bf    = (unsigned short*)alloc((size_t)SEQ * HID * 2);
  unsigned short* wis_bf  = (unsigned short*)alloc((size_t)DIN * HID * 2);  // adjacent to wig_bf: one [8192][2048] B matrix
  unsigned short* wig_bf  = (unsigned short*)alloc((size_t)DIN * HID * 2);
  unsigned short* wcat_bf = (unsigned short*)alloc((size_t)192 * DIN * 2);
  unsigned short* wdtp_bf = (unsigned short*)alloc((size_t)DIN * RNK * 2);
  unsigned short* wout_bf = (unsigned short*)alloc((size_t)HID * DIN * 2);
  float* pg    = (float*)alloc((size_t)SEQ * 8192 * 4);  // [SEQ][8192]: cols 0..4095 pre-conv states, 4096..8191 gate
  float* hs2   = (float*)alloc((size_t)SEQ * DIN * 4);   // hs post conv+silu [SEQ][DIN]
  unsigned short* hs_bf = (unsigned short*)alloc((size_t)SEQ * DIN * 2);
  float* c2    = (float*)alloc((size_t)SEQ * 192 * 4);
  float* c2p   = (float*)alloc((size_t)8 * SEQ * 192 * 4);
  unsigned short* ts_bf = (unsigned short*)alloc((size_t)SEQ * RNK * 2);
  float* dtbuf = (float*)alloc((size_t)SEQ * DIN * 4);
  unsigned short* ygT_bf = (unsigned short*)alloc((size_t)SEQ * DIN * 2);
  if (off > ws_size) return;  // workspace too small: fail loudly via validation
  // dead-buffer reuse (16 MB each): wis_bf/wig_bf dead after in-proj; dtbuf dead after scan
  float* Pbuf = (float*)wis_bf;
  float* Sbuf = (float*)wig_bf;   // phase2 overwrites with sig in-place
  float* op_part = dtbuf;         // [2][SEQ][HID] out-proj partials

  // 1) all bf16 conversions (8 elems/thread: 2x float4 load, ushort8 store)
  cvt_all<<<CV_TOT / 2048, 256, 0, stream>>>(x, wis, wig, wdt, wb, wc, wdtp, wout,
                                             x_bf, wis_bf, wig_bf, wcat_bf, wdtp_bf, wout_bf);
  // 2) merged input projection (pipelined gemm, XCD swizzle):
  //    pg[SEQ][8192] = x[SEQ][HID] x [wis;wig][8192][HID]
  gemm128<0><<<dim3(SEQ / 128, 8192 / 128), 256, 0, stream>>>(x_bf, wis_bf, pg, nullptr, SEQ, 8192, HID, HID);
  // 3) causal conv + silu + bf16 cast
  conv_silu<<<(SEQ * DIN) / 256, 256, 0, stream>>>(pg, convw, convb, hs2, hs_bf);
  // 4) ts/B/C projections, split-K x8
  gemm_nt<0><<<dim3(SEQ / 128, 192 / 64, 8), 256, 0, stream>>>(hs_bf, wcat_bf, c2p, nullptr, SEQ, 192, DIN, DIN / 8);
  reduce_ts<<<(SEQ * 192) / 256, 256, 0, stream>>>(c2p, c2, ts_bf);
  // 5) dt[SEQ][DIN] = softplus(ts[SEQ][RNK] x Wdtproj[DIN][RNK] + b)
  gemm_nt<1><<<dim3(SEQ / 128, DIN / 64), 256, 0, stream>>>(ts_bf, wdtp_bf, dtbuf, bdtp, SEQ, DIN, RNK, RNK);
  // 6) chunked selective scan (64 chunks of 16)
  scan_phase1<<<dim3(DIN / 256, CHN), 256, 0, stream>>>(dtbuf, hs2, c2, alog, Pbuf, Sbuf);
  scan_phase2<<<(DIN * NST) / 256, 256, 0, stream>>>(Pbuf, Sbuf);
  scan_phase3<<<dim3(DIN / 256, CHN), 256, 0, stream>>>(dtbuf, hs2, pg, c2, alog, Dv, Sbuf, ygT_bf);
  // 7) out-proj split-K x2: op_part[z][SEQ][HID] = ygT[SEQ][2048-slice] x Wout[HID][2048-slice]
  gemm128<0><<<dim3(SEQ / 128, HID / 128, 2), 256, 0, stream>>>(ygT_bf, wout_bf, op_part, nullptr, SEQ, HID, DIN, DIN / 2);
  reduce_out<<<(SEQ * HID) / 1024, 256, 0, stream>>>(op_part, (float*)d_out);
}

// Round 4
// 226.807 us; speedup vs baseline: 1.1434x; 1.0530x over previous
//
#include <hip/hip_runtime.h>

#define SEQ 1024
#define HID 2048
#define DIN 4096
#define NST 16
#define RNK 128
#define CHN 64
#define CLEN 16

typedef __attribute__((ext_vector_type(4))) float f32x4;
typedef __attribute__((ext_vector_type(4))) __bf16 bf16x4v;
typedef __attribute__((ext_vector_type(8))) __bf16 bf16x8v;
typedef __attribute__((ext_vector_type(8))) unsigned short u16x8;

#define GPTR(p) ((const __attribute__((address_space(1))) void*)(p))
#define LPTR(p) ((__attribute__((address_space(3))) void*)(p))

__device__ __forceinline__ unsigned short f2bf(float v) {
  unsigned u = __builtin_bit_cast(unsigned, v);
  u = (u + 0x7fffu + ((u >> 16) & 1u)) >> 16;
  return (unsigned short)u;
}
__device__ __forceinline__ float softplus_f(float x) {
  return (x > 20.f) ? x : log1pf(__expf(x));
}
__device__ __forceinline__ float silu_f(float x) {
  return x / (1.f + __expf(-x));
}

// ---------------- fp32 -> bf16 conversions, one launch, 8 elems/thread ----------------
#define CV_NX  (SEQ*HID)
#define CV_NW  (DIN*HID)
#define CV_NDT (RNK*DIN)
#define CV_NB  (NST*DIN)
#define CV_NPD (32*DIN)
#define CV_NWO (HID*DIN)
#define CV_TOT (CV_NX + 2*CV_NW + CV_NDT + 2*CV_NB + CV_NPD + CV_NDT + CV_NWO)

// All segment sizes are multiples of 512, so no wave straddles a segment
// boundary (64 lanes x 8 elems = 512). 32B load / 16B store per lane.
__global__ __launch_bounds__(256) void cvt_all(
    const float* __restrict__ x, const float* __restrict__ wis,
    const float* __restrict__ wig, const float* __restrict__ wdt,
    const float* __restrict__ wb, const float* __restrict__ wc,
    const float* __restrict__ wdtp, const float* __restrict__ wout,
    unsigned short* __restrict__ x_bf, unsigned short* __restrict__ wis_bf,
    unsigned short* __restrict__ wig_bf, unsigned short* __restrict__ wcat_bf,
    unsigned short* __restrict__ wdtp_bf, unsigned short* __restrict__ wout_bf)
{
  size_t j = ((size_t)blockIdx.x * 256 + threadIdx.x) * 8;
  const float* src = nullptr; unsigned short* dst;
  if (j < CV_NX) { src = x + j; dst = x_bf + j; }
  else if ((j -= CV_NX) < CV_NW) { src = wis + j; dst = wis_bf + j; }
  else if ((j -= CV_NW) < CV_NW) { src = wig + j; dst = wig_bf + j; }
  else if ((j -= CV_NW) < CV_NDT) { src = wdt + j; dst = wcat_bf + j; }
  else if ((j -= CV_NDT) < CV_NB) { src = wb + j; dst = wcat_bf + (size_t)128*DIN + j; }
  else if ((j -= CV_NB) < CV_NB) { src = wc + j; dst = wcat_bf + (size_t)144*DIN + j; }
  else if ((j -= CV_NB) < CV_NPD) { dst = wcat_bf + (size_t)160*DIN + j; }
  else if ((j -= CV_NPD) < CV_NDT) { src = wdtp + j; dst = wdtp_bf + j; }
  else { j -= CV_NDT; src = wout + j; dst = wout_bf + j; }
  u16x8 o = {};
  if (src) {
    f32x4 a = *(const f32x4*)src;
    f32x4 b = *(const f32x4*)(src + 4);
#pragma unroll
    for (int i = 0; i < 4; i++) { o[i] = f2bf(a[i]); o[4 + i] = f2bf(b[i]); }
  }
  *(u16x8*)dst = o;
}

// ---------------- pipelined NT GEMM: 128x128 tile, BK=32, 2-deep prefetch ----------------
// A: [M][Kstride] bf16, B: [N][Kstride] bf16, C: [M][N] fp32.
// 3 LDS buffers; counted s_waitcnt vmcnt(4) keeps the next tile's loads in
// flight across the (raw) barrier (T3/T4).
// T2 bank-conflict swizzle: LDS rows are 64B (4 x 16B slots). Physical slot
// s holds global k-chunk (s ^ f(row)), f(row) = (row>>1)&3 -- an XOR
// involution on the slot index. global_load_lds writes LDS linearly, so the
// swizzle is applied on the GLOBAL source column (rule #21: linear dest +
// inverse-swz source + swz on read). f is invariant under row+16/32/64, so
// one per-lane source offset serves all 4 staged chunks, and the read slot
// (lg ^ ((lr>>1)&3)) is constant per lane. Bank map: exactly 2 lanes per
// bank-quad (the free minimum) instead of 8.
// grid.z>1 => split-K. XCD swizzle needs gridDim.x*gridDim.y % 8 == 0.
// Requires Kiter >= 64 (nt >= 2).
template<int EPI>
__global__ __launch_bounds__(256) void gemm128(
    const unsigned short* __restrict__ Ag, const unsigned short* __restrict__ Bg,
    float* __restrict__ Cg, const float* __restrict__ bias,
    int Msz, int Nsz, int Kstride, int Kiter)
{
  __shared__ __align__(16) unsigned short As[3][128 * 32];
  __shared__ __align__(16) unsigned short Bs[3][128 * 32];
  const int kz = blockIdx.z;
  Ag += (size_t)kz * Kiter;
  Bg += (size_t)kz * Kiter;
  Cg += (size_t)kz * Msz * Nsz;
  const int nwg = gridDim.x * gridDim.y;
  const int orig = blockIdx.y * gridDim.x + blockIdx.x;
  const int swz = (orig & 7) * (nwg >> 3) + (orig >> 3);
  const int bx = swz % gridDim.x, by = swz / gridDim.x;
  const int tid = threadIdx.x;
  const int m0 = bx * 128, n0 = by * 128;
  const int lane = tid & 63, w = tid >> 6;
  const int wm = w >> 1, wn = w & 1;
  const int lg = lane >> 4, lr = lane & 15;
  const int srow = w * 32 + (lane >> 2);
  const int sch = (((lane & 3) ^ ((lane >> 3) & 3))) * 8;  // swizzled source slot
  const unsigned short* Ag0 = Ag + (size_t)(m0 + srow) * Kstride + sch;
  const unsigned short* Bg0 = Bg + (size_t)(n0 + srow) * Kstride + sch;
  const int wo = w * 1024;
  const int lgs = (lg ^ ((lr >> 1) & 3)) * 8;              // swizzled read slot

  auto stage = [&](int b, int k0) {
    __builtin_amdgcn_global_load_lds(GPTR(Ag0 + k0), LPTR(&As[b][wo]), 16, 0, 0);
    __builtin_amdgcn_global_load_lds(GPTR(Ag0 + 16 * Kstride + k0), LPTR(&As[b][wo + 512]), 16, 0, 0);
    __builtin_amdgcn_global_load_lds(GPTR(Bg0 + k0), LPTR(&Bs[b][wo]), 16, 0, 0);
    __builtin_amdgcn_global_load_lds(GPTR(Bg0 + 16 * Kstride + k0), LPTR(&Bs[b][wo + 512]), 16, 0, 0);
  };

  const int nt = Kiter >> 5;
  stage(0, 0);
  stage(1, 32);
  f32x4 acc[4][4] = {};
  int cur = 0, pf = 2;
  for (int t = 0; t < nt; ++t) {
    if (t < nt - 1) {
      asm volatile("s_waitcnt vmcnt(4)" ::: "memory");
    } else {
      asm volatile("s_waitcnt vmcnt(0)" ::: "memory");
    }
    __builtin_amdgcn_s_barrier();
    asm volatile("" ::: "memory");
    if (t + 2 < nt) stage(pf, (t + 2) * 32);
    bf16x8v af[4], bfv[4];
#pragma unroll
    for (int mi = 0; mi < 4; mi++)
      af[mi] = *(const bf16x8v*)&As[cur][(wm * 64 + mi * 16 + lr) * 32 + lgs];
#pragma unroll
    for (int ni = 0; ni < 4; ni++)
      bfv[ni] = *(const bf16x8v*)&Bs[cur][(wn * 64 + ni * 16 + lr) * 32 + lgs];
#pragma unroll
    for (int mi = 0; mi < 4; mi++)
#pragma unroll
      for (int ni = 0; ni < 4; ni++)
        acc[mi][ni] = __builtin_amdgcn_mfma_f32_16x16x32_bf16(af[mi], bfv[ni], acc[mi][ni], 0, 0, 0);
    cur = (cur == 2) ? 0 : cur + 1;
    pf = (pf == 2) ? 0 : pf + 1;
  }
#pragma unroll
  for (int mi = 0; mi < 4; mi++) {
#pragma unroll
    for (int ni = 0; ni < 4; ni++) {
      const int col = n0 + wn * 64 + ni * 16 + lr;
#pragma unroll
      for (int r = 0; r < 4; r++) {
        const int row = m0 + wm * 64 + mi * 16 + lg * 4 + r;
        float v = acc[mi][ni][r];
        if (EPI == 1) v = softplus_f(v + bias[col]);
        Cg[(size_t)row * Nsz + col] = v;
      }
    }
  }
}

// ---------------- 128x64 NT GEMM, VGPR-staged (ts/B/C projection + dt-proj) ----------------
template<int EPI>
__global__ __launch_bounds__(256) void gemm_nt(
    const unsigned short* __restrict__ Ag, const unsigned short* __restrict__ Bg,
    float* __restrict__ Cg, const float* __restrict__ bias,
    int Msz, int Nsz, int Kstride, int Kiter)
{
  __shared__ __align__(16) unsigned short As[128][40];
  __shared__ __align__(16) unsigned short Bs[64][40];
  const int kz = blockIdx.z;
  Ag += (size_t)kz * Kiter;
  Bg += (size_t)kz * Kiter;
  Cg += (size_t)kz * Msz * Nsz;
  const int tid = threadIdx.x;
  const int m0 = blockIdx.x * 128, n0 = blockIdx.y * 64;
  const int lane = tid & 63, w = tid >> 6;
  const int wm = w >> 1, wn = w & 1;
  const int lg = lane >> 4, lr = lane & 15;
  const int r4 = tid >> 2, c8 = (tid & 3) * 8;
  f32x4 acc[4][2] = {};
  for (int k0 = 0; k0 < Kiter; k0 += 32) {
    uint4 a0 = *(const uint4*)(Ag + (size_t)(m0 + r4) * Kstride + k0 + c8);
    uint4 a1 = *(const uint4*)(Ag + (size_t)(m0 + 64 + r4) * Kstride + k0 + c8);
    uint4 b0 = *(const uint4*)(Bg + (size_t)(n0 + r4) * Kstride + k0 + c8);
    *(uint4*)&As[r4][c8] = a0;
    *(uint4*)&As[64 + r4][c8] = a1;
    *(uint4*)&Bs[r4][c8] = b0;
    __syncthreads();
    bf16x8v af[4], bfr[2];
#pragma unroll
    for (int mi = 0; mi < 4; mi++) {
      const int row = wm * 64 + mi * 16 + lr;
      bf16x4v lo = *(const bf16x4v*)&As[row][4 * lg];
      bf16x4v hi = *(const bf16x4v*)&As[row][16 + 4 * lg];
      af[mi] = __builtin_shufflevector(lo, hi, 0, 1, 2, 3, 4, 5, 6, 7);
    }
#pragma unroll
    for (int ni = 0; ni < 2; ni++) {
      const int row = wn * 32 + ni * 16 + lr;
      bf16x4v lo = *(const bf16x4v*)&Bs[row][4 * lg];
      bf16x4v hi = *(const bf16x4v*)&Bs[row][16 + 4 * lg];
      bfr[ni] = __builtin_shufflevector(lo, hi, 0, 1, 2, 3, 4, 5, 6, 7);
    }
#pragma unroll
    for (int mi = 0; mi < 4; mi++)
#pragma unroll
      for (int ni = 0; ni < 2; ni++)
        acc[mi][ni] = __builtin_amdgcn_mfma_f32_16x16x32_bf16(af[mi], bfr[ni], acc[mi][ni], 0, 0, 0);
    __syncthreads();
  }
#pragma unroll
  for (int mi = 0; mi < 4; mi++) {
#pragma unroll
    for (int ni = 0; ni < 2; ni++) {
      const int col = n0 + wn * 32 + ni * 16 + lr;
#pragma unroll
      for (int r = 0; r < 4; r++) {
        const int row = m0 + wm * 64 + mi * 16 + lg * 4 + r;
        float v = acc[mi][ni][r];
        if (EPI == 1) v = softplus_f(v + bias[col]);
        Cg[(size_t)row * Nsz + col] = v;
      }
    }
  }
}

// ---------------- causal depthwise conv(K=4) + bias + silu; pg stride 8192 ----------------
__global__ __launch_bounds__(256) void conv_silu(
    const float* __restrict__ pg, const float* __restrict__ cw,
    const float* __restrict__ cb, float* __restrict__ hs,
    unsigned short* __restrict__ hs_bf)
{
  int idx = blockIdx.x * 256 + threadIdx.x;  // l*DIN + d
  int l = idx >> 12, d = idx & (DIN - 1);
  float acc = cb[d];
#pragma unroll
  for (int j = 0; j < 4; j++) {
    int ll = l + j - 3;
    float v = (ll >= 0) ? pg[(size_t)ll * 8192 + d] : 0.f;
    acc = fmaf(cw[d * 4 + j], v, acc);
  }
  float r = silu_f(acc);
  hs[idx] = r;
  hs_bf[idx] = f2bf(r);
}

// ---------------- split-K reduce for ts/B/C + ts->bf16 ----------------
__global__ __launch_bounds__(256) void reduce_ts(
    const float* __restrict__ c2p, float* __restrict__ c2,
    unsigned short* __restrict__ ts_bf)
{
  int i = blockIdx.x * 256 + threadIdx.x;  // < SEQ*192
  float s = 0.f;
#pragma unroll
  for (int z = 0; z < 8; z++) s += c2p[(size_t)z * SEQ * 192 + i];
  c2[i] = s;
  int l = i / 192, col = i - l * 192;
  if (col < 128) ts_bf[l * 128 + col] = f2bf(s);
}

// ---------------- split-K reduce for out-proj (x4, float4) ----------------
__global__ __launch_bounds__(256) void reduce_out(
    const float* __restrict__ p, float* __restrict__ out)
{
  int i = (blockIdx.x * 256 + threadIdx.x) * 4;
  float4 a = *(const float4*)&p[i];
#pragma unroll
  for (int z = 1; z < 4; z++) {
    float4 b = *(const float4*)&p[(size_t)z * SEQ * HID + i];
    a.x += b.x; a.y += b.y; a.z += b.z; a.w += b.w;
  }
  *(float4*)&out[i] = a;
}

// ---------------- chunked selective scan ----------------
__global__ __launch_bounds__(256) void scan_phase1(
    const float* __restrict__ dt, const float* __restrict__ hs,
    const float* __restrict__ c2, const float* __restrict__ alog,
    float* __restrict__ Pbuf, float* __restrict__ Sbuf)
{
  __shared__ float B_ch[CLEN][16];
  const int tid = threadIdx.x;
  const int d = blockIdx.x * 256 + tid;
  const int c = blockIdx.y;
  const int l0 = c * CLEN;
  B_ch[tid >> 4][tid & 15] = c2[(size_t)(l0 + (tid >> 4)) * 192 + 128 + (tid & 15)];
  float a[16];
#pragma unroll
  for (int i = 0; i < 16; i++) a[i] = -__expf(alog[(size_t)d * 16 + i]);
  __syncthreads();
  float s[16] = {};
  float P[16];
#pragma unroll
  for (int i = 0; i < 16; i++) P[i] = 1.f;
  for (int t = 0; t < CLEN; t++) {
    float dtv = dt[(size_t)(l0 + t) * DIN + d];
    float u = hs[(size_t)(l0 + t) * DIN + d];
    float w = dtv * u;
#pragma unroll
    for (int n = 0; n < 16; n++) {
      float dA = __expf(a[n] * dtv);
      s[n] = fmaf(dA, s[n], w * B_ch[t][n]);
      P[n] *= dA;
    }
  }
  size_t base = ((size_t)c * DIN + d) * 16;
#pragma unroll
  for (int i = 0; i < 4; i++) {
    *(float4*)&Sbuf[base + 4 * i] = *(float4*)&s[4 * i];
    *(float4*)&Pbuf[base + 4 * i] = *(float4*)&P[4 * i];
  }
}

// phase 2: serial combine; sig written IN-PLACE into Sbuf
__global__ __launch_bounds__(256) void scan_phase2(
    const float* __restrict__ Pbuf, float* __restrict__ Sbuf)
{
  size_t idx = (size_t)blockIdx.x * 256 + threadIdx.x;  // d*16+n
  const size_t stride = (size_t)DIN * 16;
  float s = 0.f;
#pragma unroll 4
  for (int c = 0; c < CHN; c++) {
    float Pv = Pbuf[c * stride + idx];
    float Sv = Sbuf[c * stride + idx];
    Sbuf[c * stride + idx] = s;
    s = fmaf(Pv, s, Sv);
  }
}

// phase 3: re-scan chunk from sig (=Sbuf), y = s.C, fused D + gate, write ygT bf16
__global__ __launch_bounds__(256) void scan_phase3(
    const float* __restrict__ dt, const float* __restrict__ hs,
    const float* __restrict__ pg, const float* __restrict__ c2,
    const float* __restrict__ alog, const float* __restrict__ Dv,
    const float* __restrict__ sig, unsigned short* __restrict__ ygT)
{
  __shared__ float B_ch[CLEN][16], C_ch[CLEN][16];
  const int tid = threadIdx.x;
  const int d = blockIdx.x * 256 + tid;
  const int c = blockIdx.y;
  const int l0 = c * CLEN;
  {
    int t = tid >> 4, n = tid & 15;
    B_ch[t][n] = c2[(size_t)(l0 + t) * 192 + 128 + n];
    C_ch[t][n] = c2[(size_t)(l0 + t) * 192 + 144 + n];
  }
  float a[16];
#pragma unroll
  for (int i = 0; i < 16; i++) a[i] = -__expf(alog[(size_t)d * 16 + i]);
  const float Dd = Dv[d];
  float s[16];
  size_t base = ((size_t)c * DIN + d) * 16;
#pragma unroll
  for (int i = 0; i < 4; i++) *(float4*)&s[4 * i] = *(const float4*)&sig[base + 4 * i];
  __syncthreads();
  for (int t = 0; t < CLEN; t++) {
    float dtv = dt[(size_t)(l0 + t) * DIN + d];
    float u = hs[(size_t)(l0 + t) * DIN + d];
    float g = pg[(size_t)(l0 + t) * 8192 + 4096 + d];
    float w = dtv * u;
    float y = 0.f;
#pragma unroll
    for (int n = 0; n < 16; n++) {
      float dA = __expf(a[n] * dtv);
      s[n] = fmaf(dA, s[n], w * B_ch[t][n]);
      y = fmaf(s[n], C_ch[t][n], y);
    }
    float o = (y + u * Dd) * silu_f(g);
    ygT[(size_t)(l0 + t) * DIN + d] = f2bf(o);
  }
}

extern "C" void kernel_launch(void* const* d_in, const int* in_sizes, int n_in,
                              void* d_out, int out_size, void* d_ws, size_t ws_size,
                              hipStream_t stream) {
  const float* x     = (const float*)d_in[0];
  const float* wis   = (const float*)d_in[1];
  const float* wig   = (const float*)d_in[2];
  const float* convw = (const float*)d_in[3];
  const float* convb = (const float*)d_in[4];
  const float* wdt   = (const float*)d_in[5];
  const float* wb    = (const float*)d_in[6];
  const float* wc    = (const float*)d_in[7];
  const float* wdtp  = (const float*)d_in[8];
  const float* bdtp  = (const float*)d_in[9];
  const float* alog  = (const float*)d_in[10];
  const float* Dv    = (const float*)d_in[11];
  const float* wout  = (const float*)d_in[12];

  char* ws = (char*)d_ws;
  size_t off = 0;
  auto alloc = [&](size_t bytes) { void* p = ws + off; off += (bytes + 255) & ~(size_t)255; return p; };
  unsigned short* x_bf    = (unsigned short*)alloc((size_t)SEQ * HID * 2);
  unsigned short* wis_bf  = (unsigned short*)alloc((size_t)DIN * HID * 2);  // adjacent to wig_bf: one [8192][2048] B matrix
  unsigned short* wig_bf  = (unsigned short*)alloc((size_t)DIN * HID * 2);
  unsigned short* wcat_bf = (unsigned short*)alloc((size_t)192 * DIN * 2);
  unsigned short* wdtp_bf = (unsigned short*)alloc((size_t)DIN * RNK * 2);
  unsigned short* wout_bf = (unsigned short*)alloc((size_t)HID * DIN * 2);
  float* pg    = (float*)alloc((size_t)SEQ * 8192 * 4);  // [SEQ][8192]: cols 0..4095 pre-conv states, 4096..8191 gate
  float* hs2   = (float*)alloc((size_t)SEQ * DIN * 4);   // hs post conv+silu [SEQ][DIN]
  unsigned short* hs_bf = (unsigned short*)alloc((size_t)SEQ * DIN * 2);
  float* c2    = (float*)alloc((size_t)SEQ * 192 * 4);
  float* c2p   = (float*)alloc((size_t)8 * SEQ * 192 * 4);
  unsigned short* ts_bf = (unsigned short*)alloc((size_t)SEQ * RNK * 2);
  float* dtbuf = (float*)alloc((size_t)SEQ * DIN * 4);
  unsigned short* ygT_bf = (unsigned short*)alloc((size_t)SEQ * DIN * 2);
  if (off > ws_size) return;  // workspace too small: fail loudly via validation
  // dead-buffer reuse: wis_bf/wig_bf (16 MB each) dead after in-proj;
  // pg (32 MB) dead after scan_phase3 -> holds the 4 out-proj partials.
  float* Pbuf = (float*)wis_bf;
  float* Sbuf = (float*)wig_bf;   // phase2 overwrites with sig in-place
  float* op_part = pg;            // [4][SEQ][HID] out-proj partials

  // 1) all bf16 conversions (8 elems/thread: 2x float4 load, ushort8 store)
  cvt_all<<<CV_TOT / 2048, 256, 0, stream>>>(x, wis, wig, wdt, wb, wc, wdtp, wout,
                                             x_bf, wis_bf, wig_bf, wcat_bf, wdtp_bf, wout_bf);
  // 2) merged input projection (pipelined gemm, XCD swizzle):
  //    pg[SEQ][8192] = x[SEQ][HID] x [wis;wig][8192][HID]
  gemm128<0><<<dim3(SEQ / 128, 8192 / 128), 256, 0, stream>>>(x_bf, wis_bf, pg, nullptr, SEQ, 8192, HID, HID);
  // 3) causal conv + silu + bf16 cast
  conv_silu<<<(SEQ * DIN) / 256, 256, 0, stream>>>(pg, convw, convb, hs2, hs_bf);
  // 4) ts/B/C projections, split-K x8
  gemm_nt<0><<<dim3(SEQ / 128, 192 / 64, 8), 256, 0, stream>>>(hs_bf, wcat_bf, c2p, nullptr, SEQ, 192, DIN, DIN / 8);
  reduce_ts<<<(SEQ * 192) / 256, 256, 0, stream>>>(c2p, c2, ts_bf);
  // 5) dt[SEQ][DIN] = softplus(ts[SEQ][RNK] x Wdtproj[DIN][RNK] + b)
  gemm_nt<1><<<dim3(SEQ / 128, DIN / 64), 256, 0, stream>>>(ts_bf, wdtp_bf, dtbuf, bdtp, SEQ, DIN, RNK, RNK);
  // 6) chunked selective scan (64 chunks of 16)
  scan_phase1<<<dim3(DIN / 256, CHN), 256, 0, stream>>>(dtbuf, hs2, c2, alog, Pbuf, Sbuf);
  scan_phase2<<<(DIN * NST) / 256, 256, 0, stream>>>(Pbuf, Sbuf);
  scan_phase3<<<dim3(DIN / 256, CHN), 256, 0, stream>>>(dtbuf, hs2, pg, c2, alog, Dv, Sbuf, ygT_bf);
  // 7) out-proj split-K x4 (512 wg -> 2 blk/CU): op_part[z][SEQ][HID] = ygT x Wout slices
  gemm128<0><<<dim3(SEQ / 128, HID / 128, 4), 256, 0, stream>>>(ygT_bf, wout_bf, op_part, nullptr, SEQ, HID, DIN, DIN / 4);
  reduce_out<<<(SEQ * HID) / 1024, 256, 0, stream>>>(op_part, (float*)d_out);
}

// Round 5
// 215.479 us; speedup vs baseline: 1.2035x; 1.0526x over previous
//
#include <hip/hip_runtime.h>

#define SEQ 1024
#define HID 2048
#define DIN 4096
#define NST 16
#define RNK 128
#define CHN 64
#define CLEN 16

typedef __attribute__((ext_vector_type(4))) float f32x4;
typedef __attribute__((ext_vector_type(4))) __bf16 bf16x4v;
typedef __attribute__((ext_vector_type(8))) __bf16 bf16x8v;
typedef __attribute__((ext_vector_type(8))) unsigned short u16x8;

#define GPTR(p) ((const __attribute__((address_space(1))) void*)(p))
#define LPTR(p) ((__attribute__((address_space(3))) void*)(p))

__device__ __forceinline__ unsigned short f2bf(float v) {
  unsigned u = __builtin_bit_cast(unsigned, v);
  u = (u + 0x7fffu + ((u >> 16) & 1u)) >> 16;
  return (unsigned short)u;
}
__device__ __forceinline__ float softplus_f(float x) {
  return (x > 20.f) ? x : log1pf(__expf(x));
}
__device__ __forceinline__ float silu_f(float x) {
  return x / (1.f + __expf(-x));
}

// ---------------- fp32 -> bf16 conversions, one launch, 8 elems/thread ----------------
#define CV_NX  (SEQ*HID)
#define CV_NW  (DIN*HID)
#define CV_NDT (RNK*DIN)
#define CV_NB  (NST*DIN)
#define CV_NPD (32*DIN)
#define CV_NWO (HID*DIN)
#define CV_TOT (CV_NX + 2*CV_NW + CV_NDT + 2*CV_NB + CV_NPD + CV_NDT + CV_NWO)

// All segment sizes are multiples of 512, so no wave straddles a segment
// boundary (64 lanes x 8 elems = 512). 32B load / 16B store per lane.
__global__ __launch_bounds__(256) void cvt_all(
    const float* __restrict__ x, const float* __restrict__ wis,
    const float* __restrict__ wig, const float* __restrict__ wdt,
    const float* __restrict__ wb, const float* __restrict__ wc,
    const float* __restrict__ wdtp, const float* __restrict__ wout,
    unsigned short* __restrict__ x_bf, unsigned short* __restrict__ wis_bf,
    unsigned short* __restrict__ wig_bf, unsigned short* __restrict__ wcat_bf,
    unsigned short* __restrict__ wdtp_bf, unsigned short* __restrict__ wout_bf)
{
  size_t j = ((size_t)blockIdx.x * 256 + threadIdx.x) * 8;
  const float* src = nullptr; unsigned short* dst;
  if (j < CV_NX) { src = x + j; dst = x_bf + j; }
  else if ((j -= CV_NX) < CV_NW) { src = wis + j; dst = wis_bf + j; }
  else if ((j -= CV_NW) < CV_NW) { src = wig + j; dst = wig_bf + j; }
  else if ((j -= CV_NW) < CV_NDT) { src = wdt + j; dst = wcat_bf + j; }
  else if ((j -= CV_NDT) < CV_NB) { src = wb + j; dst = wcat_bf + (size_t)128*DIN + j; }
  else if ((j -= CV_NB) < CV_NB) { src = wc + j; dst = wcat_bf + (size_t)144*DIN + j; }
  else if ((j -= CV_NB) < CV_NPD) { dst = wcat_bf + (size_t)160*DIN + j; }
  else if ((j -= CV_NPD) < CV_NDT) { src = wdtp + j; dst = wdtp_bf + j; }
  else { j -= CV_NDT; src = wout + j; dst = wout_bf + j; }
  u16x8 o = {};
  if (src) {
    f32x4 a = *(const f32x4*)src;
    f32x4 b = *(const f32x4*)(src + 4);
#pragma unroll
    for (int i = 0; i < 4; i++) { o[i] = f2bf(a[i]); o[4 + i] = f2bf(b[i]); }
  }
  *(u16x8*)dst = o;
}

// ---------------- pipelined NT GEMM: 128x128 tile, BK=64, 2 LDS buffers ----------------
// A: [M][Kstride] bf16, B: [N][Kstride] bf16, C: [M][N] fp32.
// Per K-step (one barrier): vmcnt(0) [tile t landed -- its loads had a FULL
// previous step in flight]; s_barrier; stage tile t+1 into buf^1 (safe: buf^1
// was last read in step t-1, fenced by this barrier); 16x ds_read_b128 +
// 32x MFMA on buf[cur]. BK=64 halves the step count vs BK=32: 2x work per
// synchronization point (the latency-bound cost at 2 blocks/CU).
// LDS 64 KB -> 2 blocks/CU, which equals the grid-imposed residency anyway.
// T2 swizzle, 8 slots/row (rows are 128 B = 8 x 16 B slots): physical slot
// s at row r holds global k-chunk s ^ (r&7). global_load_lds writes linearly
// (dest = base + lane*16, row r&7 = lane>>3), so the swizzle is applied on
// the GLOBAL source slot (lane&7)^(lane>>3) (rule #21); read slot is
// (kk*4+lg)^(lr&7). Banks: 2 lanes/bank (free minimum).
// grid.z>1 => split-K. XCD swizzle needs gridDim.x*gridDim.y % 8 == 0.
// Requires Kiter % 64 == 0, Kiter >= 128.
template<int EPI>
__global__ __launch_bounds__(256) void gemm128(
    const unsigned short* __restrict__ Ag, const unsigned short* __restrict__ Bg,
    float* __restrict__ Cg, const float* __restrict__ bias,
    int Msz, int Nsz, int Kstride, int Kiter)
{
  __shared__ __align__(16) unsigned short As[2][128 * 64];
  __shared__ __align__(16) unsigned short Bs[2][128 * 64];
  const int kz = blockIdx.z;
  Ag += (size_t)kz * Kiter;
  Bg += (size_t)kz * Kiter;
  Cg += (size_t)kz * Msz * Nsz;
  const int nwg = gridDim.x * gridDim.y;
  const int orig = blockIdx.y * gridDim.x + blockIdx.x;
  const int swz = (orig & 7) * (nwg >> 3) + (orig >> 3);
  const int bx = swz % gridDim.x, by = swz / gridDim.x;
  const int tid = threadIdx.x;
  const int m0 = bx * 128, n0 = by * 128;
  const int lane = tid & 63, w = tid >> 6;
  const int wm = w >> 1, wn = w & 1;
  const int lg = lane >> 4, lr = lane & 15;
  // staging: thread covers rows w*32 + i*8 + (lane>>3), i=0..3; 16B per lane.
  const int srow = w * 32 + (lane >> 3);
  const int sslot = (lane & 7) ^ (lane >> 3);      // swizzled global k-slot
  const unsigned short* Ag0 = Ag + (size_t)(m0 + srow) * Kstride + sslot * 8;
  const unsigned short* Bg0 = Bg + (size_t)(n0 + srow) * Kstride + sslot * 8;
  const int ldso = w * 2048;                        // ushort idx of wave chunk

  auto stage = [&](int b, int k0) {
#pragma unroll
    for (int i = 0; i < 4; i++)
      __builtin_amdgcn_global_load_lds(GPTR(Ag0 + (size_t)(i * 8) * Kstride + k0),
                                       LPTR(&As[b][ldso + i * 512]), 16, 0, 0);
#pragma unroll
    for (int i = 0; i < 4; i++)
      __builtin_amdgcn_global_load_lds(GPTR(Bg0 + (size_t)(i * 8) * Kstride + k0),
                                       LPTR(&Bs[b][ldso + i * 512]), 16, 0, 0);
  };

  const int nt = Kiter >> 6;
  stage(0, 0);
  f32x4 acc[4][4] = {};
  int cur = 0;
  const int rsw = lr & 7;                           // read-side XOR key
  for (int t = 0; t < nt; ++t) {
    asm volatile("s_waitcnt vmcnt(0)" ::: "memory");
    __builtin_amdgcn_s_barrier();
    asm volatile("" ::: "memory");
    if (t + 1 < nt) stage(cur ^ 1, (t + 1) * 64);
    bf16x8v af0[4], bf0[4], af1[4], bf1[4];
#pragma unroll
    for (int mi = 0; mi < 4; mi++) {
      const int row = (wm * 64 + mi * 16 + lr) * 64;
      af0[mi] = *(const bf16x8v*)&As[cur][row + ((0 * 4 + lg) ^ rsw) * 8];
      af1[mi] = *(const bf16x8v*)&As[cur][row + ((1 * 4 + lg) ^ rsw) * 8];
    }
#pragma unroll
    for (int ni = 0; ni < 4; ni++) {
      const int row = (wn * 64 + ni * 16 + lr) * 64;
      bf0[ni] = *(const bf16x8v*)&Bs[cur][row + ((0 * 4 + lg) ^ rsw) * 8];
      bf1[ni] = *(const bf16x8v*)&Bs[cur][row + ((1 * 4 + lg) ^ rsw) * 8];
    }
#pragma unroll
    for (int mi = 0; mi < 4; mi++)
#pragma unroll
      for (int ni = 0; ni < 4; ni++)
        acc[mi][ni] = __builtin_amdgcn_mfma_f32_16x16x32_bf16(af0[mi], bf0[ni], acc[mi][ni], 0, 0, 0);
#pragma unroll
    for (int mi = 0; mi < 4; mi++)
#pragma unroll
      for (int ni = 0; ni < 4; ni++)
        acc[mi][ni] = __builtin_amdgcn_mfma_f32_16x16x32_bf16(af1[mi], bf1[ni], acc[mi][ni], 0, 0, 0);
    cur ^= 1;
  }
#pragma unroll
  for (int mi = 0; mi < 4; mi++) {
#pragma unroll
    for (int ni = 0; ni < 4; ni++) {
      const int col = n0 + wn * 64 + ni * 16 + lr;
#pragma unroll
      for (int r = 0; r < 4; r++) {
        const int row = m0 + wm * 64 + mi * 16 + lg * 4 + r;
        float v = acc[mi][ni][r];
        if (EPI == 1) v = softplus_f(v + bias[col]);
        Cg[(size_t)row * Nsz + col] = v;
      }
    }
  }
}

// ---------------- 128x64 NT GEMM, VGPR-staged (ts/B/C projection + dt-proj) ----------------
template<int EPI>
__global__ __launch_bounds__(256) void gemm_nt(
    const unsigned short* __restrict__ Ag, const unsigned short* __restrict__ Bg,
    float* __restrict__ Cg, const float* __restrict__ bias,
    int Msz, int Nsz, int Kstride, int Kiter)
{
  __shared__ __align__(16) unsigned short As[128][40];
  __shared__ __align__(16) unsigned short Bs[64][40];
  const int kz = blockIdx.z;
  Ag += (size_t)kz * Kiter;
  Bg += (size_t)kz * Kiter;
  Cg += (size_t)kz * Msz * Nsz;
  const int tid = threadIdx.x;
  const int m0 = blockIdx.x * 128, n0 = blockIdx.y * 64;
  const int lane = tid & 63, w = tid >> 6;
  const int wm = w >> 1, wn = w & 1;
  const int lg = lane >> 4, lr = lane & 15;
  const int r4 = tid >> 2, c8 = (tid & 3) * 8;
  f32x4 acc[4][2] = {};
  for (int k0 = 0; k0 < Kiter; k0 += 32) {
    uint4 a0 = *(const uint4*)(Ag + (size_t)(m0 + r4) * Kstride + k0 + c8);
    uint4 a1 = *(const uint4*)(Ag + (size_t)(m0 + 64 + r4) * Kstride + k0 + c8);
    uint4 b0 = *(const uint4*)(Bg + (size_t)(n0 + r4) * Kstride + k0 + c8);
    *(uint4*)&As[r4][c8] = a0;
    *(uint4*)&As[64 + r4][c8] = a1;
    *(uint4*)&Bs[r4][c8] = b0;
    __syncthreads();
    bf16x8v af[4], bfr[2];
#pragma unroll
    for (int mi = 0; mi < 4; mi++) {
      const int row = wm * 64 + mi * 16 + lr;
      bf16x4v lo = *(const bf16x4v*)&As[row][4 * lg];
      bf16x4v hi = *(const bf16x4v*)&As[row][16 + 4 * lg];
      af[mi] = __builtin_shufflevector(lo, hi, 0, 1, 2, 3, 4, 5, 6, 7);
    }
#pragma unroll
    for (int ni = 0; ni < 2; ni++) {
      const int row = wn * 32 + ni * 16 + lr;
      bf16x4v lo = *(const bf16x4v*)&Bs[row][4 * lg];
      bf16x4v hi = *(const bf16x4v*)&Bs[row][16 + 4 * lg];
      bfr[ni] = __builtin_shufflevector(lo, hi, 0, 1, 2, 3, 4, 5, 6, 7);
    }
#pragma unroll
    for (int mi = 0; mi < 4; mi++)
#pragma unroll
      for (int ni = 0; ni < 2; ni++)
        acc[mi][ni] = __builtin_amdgcn_mfma_f32_16x16x32_bf16(af[mi], bfr[ni], acc[mi][ni], 0, 0, 0);
    __syncthreads();
  }
#pragma unroll
  for (int mi = 0; mi < 4; mi++) {
#pragma unroll
    for (int ni = 0; ni < 2; ni++) {
      const int col = n0 + wn * 32 + ni * 16 + lr;
#pragma unroll
      for (int r = 0; r < 4; r++) {
        const int row = m0 + wm * 64 + mi * 16 + lg * 4 + r;
        float v = acc[mi][ni][r];
        if (EPI == 1) v = softplus_f(v + bias[col]);
        Cg[(size_t)row * Nsz + col] = v;
      }
    }
  }
}

// ---------------- causal depthwise conv(K=4) + bias + silu; pg stride 8192 ----------------
__global__ __launch_bounds__(256) void conv_silu(
    const float* __restrict__ pg, const float* __restrict__ cw,
    const float* __restrict__ cb, float* __restrict__ hs,
    unsigned short* __restrict__ hs_bf)
{
  int idx = blockIdx.x * 256 + threadIdx.x;  // l*DIN + d
  int l = idx >> 12, d = idx & (DIN - 1);
  float acc = cb[d];
#pragma unroll
  for (int j = 0; j < 4; j++) {
    int ll = l + j - 3;
    float v = (ll >= 0) ? pg[(size_t)ll * 8192 + d] : 0.f;
    acc = fmaf(cw[d * 4 + j], v, acc);
  }
  float r = silu_f(acc);
  hs[idx] = r;
  hs_bf[idx] = f2bf(r);
}

// ---------------- split-K reduce for ts/B/C + ts->bf16 ----------------
__global__ __launch_bounds__(256) void reduce_ts(
    const float* __restrict__ c2p, float* __restrict__ c2,
    unsigned short* __restrict__ ts_bf)
{
  int i = blockIdx.x * 256 + threadIdx.x;  // < SEQ*192
  float s = 0.f;
#pragma unroll
  for (int z = 0; z < 8; z++) s += c2p[(size_t)z * SEQ * 192 + i];
  c2[i] = s;
  int l = i / 192, col = i - l * 192;
  if (col < 128) ts_bf[l * 128 + col] = f2bf(s);
}

// ---------------- split-K reduce for out-proj (x4, float4) ----------------
__global__ __launch_bounds__(256) void reduce_out(
    const float* __restrict__ p, float* __restrict__ out)
{
  int i = (blockIdx.x * 256 + threadIdx.x) * 4;
  float4 a = *(const float4*)&p[i];
#pragma unroll
  for (int z = 1; z < 4; z++) {
    float4 b = *(const float4*)&p[(size_t)z * SEQ * HID + i];
    a.x += b.x; a.y += b.y; a.z += b.z; a.w += b.w;
  }
  *(float4*)&out[i] = a;
}

// ---------------- chunked selective scan ----------------
__global__ __launch_bounds__(256) void scan_phase1(
    const float* __restrict__ dt, const float* __restrict__ hs,
    const float* __restrict__ c2, const float* __restrict__ alog,
    float* __restrict__ Pbuf, float* __restrict__ Sbuf)
{
  __shared__ float B_ch[CLEN][16];
  const int tid = threadIdx.x;
  const int d = blockIdx.x * 256 + tid;
  const int c = blockIdx.y;
  const int l0 = c * CLEN;
  B_ch[tid >> 4][tid & 15] = c2[(size_t)(l0 + (tid >> 4)) * 192 + 128 + (tid & 15)];
  float a[16];
#pragma unroll
  for (int i = 0; i < 16; i++) a[i] = -__expf(alog[(size_t)d * 16 + i]);
  __syncthreads();
  float s[16] = {};
  float P[16];
#pragma unroll
  for (int i = 0; i < 16; i++) P[i] = 1.f;
  for (int t = 0; t < CLEN; t++) {
    float dtv = dt[(size_t)(l0 + t) * DIN + d];
    float u = hs[(size_t)(l0 + t) * DIN + d];
    float w = dtv * u;
#pragma unroll
    for (int n = 0; n < 16; n++) {
      float dA = __expf(a[n] * dtv);
      s[n] = fmaf(dA, s[n], w * B_ch[t][n]);
      P[n] *= dA;
    }
  }
  size_t base = ((size_t)c * DIN + d) * 16;
#pragma unroll
  for (int i = 0; i < 4; i++) {
    *(float4*)&Sbuf[base + 4 * i] = *(float4*)&s[4 * i];
    *(float4*)&Pbuf[base + 4 * i] = *(float4*)&P[4 * i];
  }
}

// phase 2: serial combine; sig written IN-PLACE into Sbuf
__global__ __launch_bounds__(256) void scan_phase2(
    const float* __restrict__ Pbuf, float* __restrict__ Sbuf)
{
  size_t idx = (size_t)blockIdx.x * 256 + threadIdx.x;  // d*16+n
  const size_t stride = (size_t)DIN * 16;
  float s = 0.f;
#pragma unroll 4
  for (int c = 0; c < CHN; c++) {
    float Pv = Pbuf[c * stride + idx];
    float Sv = Sbuf[c * stride + idx];
    Sbuf[c * stride + idx] = s;
    s = fmaf(Pv, s, Sv);
  }
}

// phase 3: re-scan chunk from sig (=Sbuf), y = s.C, fused D + gate, write ygT bf16
__global__ __launch_bounds__(256) void scan_phase3(
    const float* __restrict__ dt, const float* __restrict__ hs,
    const float* __restrict__ pg, const float* __restrict__ c2,
    const float* __restrict__ alog, const float* __restrict__ Dv,
    const float* __restrict__ sig, unsigned short* __restrict__ ygT)
{
  __shared__ float B_ch[CLEN][16], C_ch[CLEN][16];
  const int tid = threadIdx.x;
  const int d = blockIdx.x * 256 + tid;
  const int c = blockIdx.y;
  const int l0 = c * CLEN;
  {
    int t = tid >> 4, n = tid & 15;
    B_ch[t][n] = c2[(size_t)(l0 + t) * 192 + 128 + n];
    C_ch[t][n] = c2[(size_t)(l0 + t) * 192 + 144 + n];
  }
  float a[16];
#pragma unroll
  for (int i = 0; i < 16; i++) a[i] = -__expf(alog[(size_t)d * 16 + i]);
  const float Dd = Dv[d];
  float s[16];
  size_t base = ((size_t)c * DIN + d) * 16;
#pragma unroll
  for (int i = 0; i < 4; i++) *(float4*)&s[4 * i] = *(const float4*)&sig[base + 4 * i];
  __syncthreads();
  for (int t = 0; t < CLEN; t++) {
    float dtv = dt[(size_t)(l0 + t) * DIN + d];
    float u = hs[(size_t)(l0 + t) * DIN + d];
    float g = pg[(size_t)(l0 + t) * 8192 + 4096 + d];
    float w = dtv * u;
    float y = 0.f;
#pragma unroll
    for (int n = 0; n < 16; n++) {
      float dA = __expf(a[n] * dtv);
      s[n] = fmaf(dA, s[n], w * B_ch[t][n]);
      y = fmaf(s[n], C_ch[t][n], y);
    }
    float o = (y + u * Dd) * silu_f(g);
    ygT[(size_t)(l0 + t) * DIN + d] = f2bf(o);
  }
}

extern "C" void kernel_launch(void* const* d_in, const int* in_sizes, int n_in,
                              void* d_out, int out_size, void* d_ws, size_t ws_size,
                              hipStream_t stream) {
  const float* x     = (const float*)d_in[0];
  const float* wis   = (const float*)d_in[1];
  const float* wig   = (const float*)d_in[2];
  const float* convw = (const float*)d_in[3];
  const float* convb = (const float*)d_in[4];
  const float* wdt   = (const float*)d_in[5];
  const float* wb    = (const float*)d_in[6];
  const float* wc    = (const float*)d_in[7];
  const float* wdtp  = (const float*)d_in[8];
  const float* bdtp  = (const float*)d_in[9];
  const float* alog  = (const float*)d_in[10];
  const float* Dv    = (const float*)d_in[11];
  const float* wout  = (const float*)d_in[12];

  char* ws = (char*)d_ws;
  size_t off = 0;
  auto alloc = [&](size_t bytes) { void* p = ws + off; off += (bytes + 255) & ~(size_t)255; return p; };
  unsigned short* x_bf    = (unsigned short*)alloc((size_t)SEQ * HID * 2);
  unsigned short* wis_bf  = (unsigned short*)alloc((size_t)DIN * HID * 2);  // adjacent to wig_bf: one [8192][2048] B matrix
  unsigned short* wig_bf  = (unsigned short*)alloc((size_t)DIN * HID * 2);
  unsigned short* wcat_bf = (unsigned short*)alloc((size_t)192 * DIN * 2);
  unsigned short* wdtp_bf = (unsigned short*)alloc((size_t)DIN * RNK * 2);
  unsigned short* wout_bf = (unsigned short*)alloc((size_t)HID * DIN * 2);
  float* pg    = (float*)alloc((size_t)SEQ * 8192 * 4);  // [SEQ][8192]: cols 0..4095 pre-conv states, 4096..8191 gate
  float* hs2   = (float*)alloc((size_t)SEQ * DIN * 4);   // hs post conv+silu [SEQ][DIN]
  unsigned short* hs_bf = (unsigned short*)alloc((size_t)SEQ * DIN * 2);
  float* c2    = (float*)alloc((size_t)SEQ * 192 * 4);
  float* c2p   = (float*)alloc((size_t)8 * SEQ * 192 * 4);
  unsigned short* ts_bf = (unsigned short*)alloc((size_t)SEQ * RNK * 2);
  float* dtbuf = (float*)alloc((size_t)SEQ * DIN * 4);
  unsigned short* ygT_bf = (unsigned short*)alloc((size_t)SEQ * DIN * 2);
  if (off > ws_size) return;  // workspace too small: fail loudly via validation
  // dead-buffer reuse: wis_bf/wig_bf (16 MB each) dead after in-proj;
  // pg (32 MB) dead after scan_phase3 -> holds the 4 out-proj partials.
  float* Pbuf = (float*)wis_bf;
  float* Sbuf = (float*)wig_bf;   // phase2 overwrites with sig in-place
  float* op_part = pg;            // [4][SEQ][HID] out-proj partials

  // 1) all bf16 conversions (8 elems/thread: 2x float4 load, ushort8 store)
  cvt_all<<<CV_TOT / 2048, 256, 0, stream>>>(x, wis, wig, wdt, wb, wc, wdtp, wout,
                                             x_bf, wis_bf, wig_bf, wcat_bf, wdtp_bf, wout_bf);
  // 2) merged input projection (BK=64 pipelined gemm, XCD swizzle):
  //    pg[SEQ][8192] = x[SEQ][HID] x [wis;wig][8192][HID]
  gemm128<0><<<dim3(SEQ / 128, 8192 / 128), 256, 0, stream>>>(x_bf, wis_bf, pg, nullptr, SEQ, 8192, HID, HID);
  // 3) causal conv + silu + bf16 cast
  conv_silu<<<(SEQ * DIN) / 256, 256, 0, stream>>>(pg, convw, convb, hs2, hs_bf);
  // 4) ts/B/C projections, split-K x8
  gemm_nt<0><<<dim3(SEQ / 128, 192 / 64, 8), 256, 0, stream>>>(hs_bf, wcat_bf, c2p, nullptr, SEQ, 192, DIN, DIN / 8);
  reduce_ts<<<(SEQ * 192) / 256, 256, 0, stream>>>(c2p, c2, ts_bf);
  // 5) dt[SEQ][DIN] = softplus(ts[SEQ][RNK] x Wdtproj[DIN][RNK] + b)
  gemm_nt<1><<<dim3(SEQ / 128, DIN / 64), 256, 0, stream>>>(ts_bf, wdtp_bf, dtbuf, bdtp, SEQ, DIN, RNK, RNK);
  // 6) chunked selective scan (64 chunks of 16)
  scan_phase1<<<dim3(DIN / 256, CHN), 256, 0, stream>>>(dtbuf, hs2, c2, alog, Pbuf, Sbuf);
  scan_phase2<<<(DIN * NST) / 256, 256, 0, stream>>>(Pbuf, Sbuf);
  scan_phase3<<<dim3(DIN / 256, CHN), 256, 0, stream>>>(dtbuf, hs2, pg, c2, alog, Dv, Sbuf, ygT_bf);
  // 7) out-proj split-K x4 (512 wg): op_part[z][SEQ][HID] = ygT x Wout slices (K=1024 each)
  gemm128<0><<<dim3(SEQ / 128, HID / 128, 4), 256, 0, stream>>>(ygT_bf, wout_bf, op_part, nullptr, SEQ, HID, DIN, DIN / 4);
  reduce_out<<<(SEQ * HID) / 1024, 256, 0, stream>>>(op_part, (float*)d_out);
}